// Round 3
// baseline (201.274 us; speedup 1.0000x reference)
//
#include <hip/hip_runtime.h>

// ---------------------------------------------------------------------------
// KAN-conv MLP. Cardinal cubic B-spline: basis_j(x) = B3(u - j), u = 2.5x+5.5,
// only 4 taps nonzero. Per block: featurize G images once into LDS as bf16
// 10-slot records [B0..B7, silu, 0] (5 packed uints, 20 B). Compute threads
// each handle ONE position in TWO images -> weight s_loads amortized 2x.
// Merged weights V[c][ky][kx][j9][o] (j8 = base weight) built by k_prep.
// ---------------------------------------------------------------------------

__device__ __forceinline__ unsigned short f2bf(float x) {
  unsigned int b = __float_as_uint(x);
  b = b + 0x7fffu + ((b >> 16) & 1u);          // RNE
  return (unsigned short)(b >> 16);
}
__device__ __forceinline__ float bflo(unsigned int u) { return __uint_as_float(u << 16); }
__device__ __forceinline__ float bfhi(unsigned int u) { return __uint_as_float(u & 0xffff0000u); }

// All LDS stores through ushort view (no uint/ushort alias mixing).
__device__ __forceinline__ void feat_store(float v, unsigned short* __restrict__ sp) {
  float s = v / (1.0f + __expf(-v));
  #pragma unroll
  for (int j = 0; j < 8; ++j) sp[j] = 0;
  sp[8] = f2bf(s);
  sp[9] = 0;
  float u = fmaf(v, 2.5f, 5.5f);
  if (u >= 0.0f && u < 11.0f) {
    float tf = floorf(u);
    float f = u - tf, f2 = f * f, f3 = f2 * f, om = 1.0f - f;
    const float c6 = 1.0f / 6.0f;
    float w0 = om * om * om * c6;
    float w1 = (3.0f * f3 - 6.0f * f2 + 4.0f) * c6;
    float w2 = (-3.0f * f3 + 3.0f * f2 + 3.0f * f + 1.0f) * c6;
    float w3 = f3 * c6;
    int t = (int)tf;                           // 0..10; basis idx kept in [0,7]
    if (t >= 3)           sp[t - 3] = f2bf(w0);
    if (t >= 2 && t <= 9) sp[t - 2] = f2bf(w1);
    if (t >= 1 && t <= 8) sp[t - 1] = f2bf(w2);
    if (t <= 7)           sp[t]     = f2bf(w3);
  }
}

// ---------------- weight prep: V[c][ky][kx][j(9)][o], j8 = base -------------
__global__ __launch_bounds__(256) void k_prep(
    const float* __restrict__ bw1, const float* __restrict__ sw1,
    const float* __restrict__ bw2, const float* __restrict__ sw2,
    const float* __restrict__ bw3, const float* __restrict__ sw3,
    float* __restrict__ V1, float* __restrict__ V2, float* __restrict__ V3) {
  int t = blockIdx.x * 256 + threadIdx.x;
  if (t < 405) {  // L1: CIN=1, COUT=5
    int o = t % 5, j = (t / 5) % 9, kx = (t / 45) % 3, ky = t / 135;
    int in = ky * 3 + kx;
    V1[t] = (j < 8) ? sw1[(o * 9 + in) * 8 + j] : bw1[o * 9 + in];
  }
  if (t < 2025) { // L2: CIN=5, COUT=5
    int o = t % 5, j = (t / 5) % 9, kx = (t / 45) % 3, ky = (t / 135) % 3, c = t / 405;
    int in = c * 9 + ky * 3 + kx;
    V2[t] = (j < 8) ? sw2[(o * 45 + in) * 8 + j] : bw2[o * 45 + in];
  }
  if (t < 810) {  // L3: CIN=5, COUT=2
    int o = t % 2, j = (t / 2) % 9, kx = (t / 18) % 3, ky = (t / 54) % 3, c = t / 162;
    int in = c * 9 + ky * 3 + kx;
    V3[t] = (j < 8) ? sw3[(o * 45 + in) * 8 + j] : bw3[o * 45 + in];
  }
}

// ---------------- conv1 (1->5) + 2x2 maxpool, 2 images/block ----------------
__global__ __launch_bounds__(256) void k_conv1_pool(
    const float* __restrict__ x, const float* __restrict__ Wd,
    float* __restrict__ h1) {
  __shared__ unsigned int phi[2 * 784 * 5];    // 31,360 B
  __shared__ float convo[2 * 5 * 676];         // 27,040 B
  unsigned short* phs = (unsigned short*)phi;
  const int b0 = blockIdx.x * 2;
  for (int l = threadIdx.x; l < 2 * 784; l += 256)
    feat_store(x[b0 * 784 + l], &phs[l * 10]);
  __syncthreads();
  for (int it = threadIdx.x; it < 676; it += 256) {
    int y = it / 26, xx = it % 26;
    float acc[2][5];
    #pragma unroll
    for (int i = 0; i < 2; ++i)
      #pragma unroll
      for (int o = 0; o < 5; ++o) acc[i][o] = 0.0f;
    #pragma unroll 1
    for (int ky = 0; ky < 3; ++ky) {
      const float* wp = Wd + ky * 135;         // [kx][j9][o5]
      #pragma unroll
      for (int i = 0; i < 2; ++i) {
        const unsigned int* up = &phi[(i * 784 + (y + ky) * 28 + xx) * 5];
        unsigned int u[15];
        #pragma unroll
        for (int q = 0; q < 15; ++q) u[q] = up[q];
        #pragma unroll
        for (int kx = 0; kx < 3; ++kx) {
          float ph[9];
          ph[0] = bflo(u[kx * 5 + 0]); ph[1] = bfhi(u[kx * 5 + 0]);
          ph[2] = bflo(u[kx * 5 + 1]); ph[3] = bfhi(u[kx * 5 + 1]);
          ph[4] = bflo(u[kx * 5 + 2]); ph[5] = bfhi(u[kx * 5 + 2]);
          ph[6] = bflo(u[kx * 5 + 3]); ph[7] = bfhi(u[kx * 5 + 3]);
          ph[8] = bflo(u[kx * 5 + 4]);
          #pragma unroll
          for (int j = 0; j < 9; ++j)
            #pragma unroll
            for (int o = 0; o < 5; ++o)
              acc[i][o] = fmaf(ph[j], wp[(kx * 9 + j) * 5 + o], acc[i][o]);
        }
      }
    }
    #pragma unroll
    for (int i = 0; i < 2; ++i)
      #pragma unroll
      for (int o = 0; o < 5; ++o) convo[(i * 5 + o) * 676 + it] = acc[i][o];
  }
  __syncthreads();
  for (int l = threadIdx.x; l < 1690; l += 256) {
    int i = l / 845, r = l % 845, o = r / 169, p = r % 169;
    int py = p / 13, px = p % 13;
    const float* cp = &convo[(i * 5 + o) * 676 + py * 52 + px * 2];
    float m = fmaxf(fmaxf(cp[0], cp[1]), fmaxf(cp[26], cp[27]));
    h1[((b0 + i) * 5 + o) * 169 + p] = m;
  }
}

// ---------------- generic KAN conv, G images/block, 2 images/thread ---------
template <int CIN, int HIN, int COUT, int G>
__global__ __launch_bounds__(256) void k_kanconv(
    const float* __restrict__ hin, const float* __restrict__ Wd,
    float* __restrict__ hout) {
  constexpr int HOUT = HIN - 2;
  constexpr int NPIX = CIN * HIN * HIN;
  __shared__ unsigned int phi[G * NPIX * 5];
  unsigned short* phs = (unsigned short*)phi;
  const int b0 = blockIdx.x * G;
  for (int l = threadIdx.x; l < G * NPIX; l += 256)
    feat_store(hin[b0 * NPIX + l], &phs[l * 10]);
  __syncthreads();
  constexpr int NITEM = (G / 2) * HOUT * HOUT;
  int it = threadIdx.x;
  if (it >= NITEM) return;
  int ip = it / (HOUT * HOUT), pos = it % (HOUT * HOUT);
  int y = pos / HOUT, x = pos % HOUT;
  float acc[2][COUT];
  #pragma unroll
  for (int i = 0; i < 2; ++i)
    #pragma unroll
    for (int o = 0; o < COUT; ++o) acc[i][o] = 0.0f;
  #pragma unroll 1
  for (int cky = 0; cky < CIN * 3; ++cky) {
    int c = cky / 3, ky = cky % 3;
    const float* wp = Wd + cky * 27 * COUT;    // [kx][j9][o]
    #pragma unroll
    for (int i = 0; i < 2; ++i) {
      int img = ip * 2 + i;
      const unsigned int* up = &phi[(((img * CIN + c) * HIN + (y + ky)) * HIN + x) * 5];
      unsigned int u[15];
      #pragma unroll
      for (int q = 0; q < 15; ++q) u[q] = up[q];
      #pragma unroll
      for (int kx = 0; kx < 3; ++kx) {
        float ph[9];
        ph[0] = bflo(u[kx * 5 + 0]); ph[1] = bfhi(u[kx * 5 + 0]);
        ph[2] = bflo(u[kx * 5 + 1]); ph[3] = bfhi(u[kx * 5 + 1]);
        ph[4] = bflo(u[kx * 5 + 2]); ph[5] = bfhi(u[kx * 5 + 2]);
        ph[6] = bflo(u[kx * 5 + 3]); ph[7] = bfhi(u[kx * 5 + 3]);
        ph[8] = bflo(u[kx * 5 + 4]);
        #pragma unroll
        for (int j = 0; j < 9; ++j)
          #pragma unroll
          for (int o = 0; o < COUT; ++o)
            acc[i][o] = fmaf(ph[j], wp[(kx * 9 + j) * COUT + o], acc[i][o]);
      }
    }
  }
  #pragma unroll
  for (int i = 0; i < 2; ++i)
    #pragma unroll
    for (int o = 0; o < COUT; ++o)
      hout[(((b0 + ip * 2 + i) * COUT + o) * HOUT + y) * HOUT + x] = acc[i][o];
}

// ---------------- FC1: [2048,162]x[500,162]^T + b, ReLU (32x64 tiles) -------
__global__ __launch_bounds__(256) void k_fc1(
    const float* __restrict__ A, const float* __restrict__ W,
    const float* __restrict__ bias, float* __restrict__ out) {
  __shared__ float As[16][34];
  __shared__ float Ws[16][68];
  int bm = (blockIdx.x & 63) * 32;
  int bn = (blockIdx.x >> 6) * 64;
  int tid = threadIdx.x;
  int tn = tid & 15, tm = tid >> 4;
  float acc[2][4];
  #pragma unroll
  for (int i = 0; i < 2; ++i)
    #pragma unroll
    for (int j = 0; j < 4; ++j) acc[i][j] = 0.0f;
  for (int k0 = 0; k0 < 162; k0 += 16) {
    #pragma unroll
    for (int e = 0; e < 2; ++e) {
      int l = tid + e * 256;                   // 0..511
      int k = l & 15, m = l >> 4;              // coalesced in k
      int gk = k0 + k;
      As[k][m] = (gk < 162) ? A[(bm + m) * 162 + gk] : 0.0f;
    }
    #pragma unroll
    for (int e = 0; e < 4; ++e) {
      int l = tid + e * 256;                   // 0..1023
      int k = l & 15, n = l >> 4;
      int gk = k0 + k, gn = bn + n;
      Ws[k][n] = (gk < 162 && gn < 500) ? W[gn * 162 + gk] : 0.0f;
    }
    __syncthreads();
    #pragma unroll
    for (int k = 0; k < 16; ++k) {
      float a0 = As[k][tm * 2], a1 = As[k][tm * 2 + 1];
      float4 wv = *(const float4*)&Ws[k][tn * 4];
      float w4[4] = {wv.x, wv.y, wv.z, wv.w};
      #pragma unroll
      for (int j = 0; j < 4; ++j) {
        acc[0][j] = fmaf(a0, w4[j], acc[0][j]);
        acc[1][j] = fmaf(a1, w4[j], acc[1][j]);
      }
    }
    __syncthreads();
  }
  #pragma unroll
  for (int i = 0; i < 2; ++i) {
    int m = bm + tm * 2 + i;
    #pragma unroll
    for (int j = 0; j < 4; ++j) {
      int n = bn + tn * 4 + j;
      if (n < 500) {
        float v = acc[i][j] + bias[n];
        out[m * 500 + n] = v > 0.0f ? v : 0.0f;
      }
    }
  }
}

// ---------------- FC2: [2048,500]x[10,500]^T + b ---------------------------
__global__ __launch_bounds__(256) void k_fc2(
    const float* __restrict__ H, const float* __restrict__ W2,
    const float* __restrict__ b2, float* __restrict__ out) {
  int gtid = blockIdx.x * 256 + threadIdx.x;
  int b = gtid / 64, lane = gtid % 64;
  if (b >= 2048) return;
  float acc[10];
  #pragma unroll
  for (int o = 0; o < 10; ++o) acc[o] = 0.0f;
  for (int k = lane; k < 500; k += 64) {
    float a = H[b * 500 + k];
    #pragma unroll
    for (int o = 0; o < 10; ++o) acc[o] = fmaf(a, W2[o * 500 + k], acc[o]);
  }
  #pragma unroll
  for (int off = 32; off > 0; off >>= 1) {
    #pragma unroll
    for (int o = 0; o < 10; ++o) acc[o] += __shfl_down(acc[o], off);
  }
  if (lane == 0) {
    #pragma unroll
    for (int o = 0; o < 10; ++o) out[b * 10 + o] = acc[o] + b2[o];
  }
}

// ---------------------------------------------------------------------------
extern "C" void kernel_launch(void* const* d_in, const int* in_sizes, int n_in,
                              void* d_out, int out_size, void* d_ws, size_t ws_size,
                              hipStream_t stream) {
  (void)in_sizes; (void)n_in; (void)out_size; (void)ws_size;
  const float* x   = (const float*)d_in[0];
  const float* bw1 = (const float*)d_in[1];
  const float* sw1 = (const float*)d_in[2];
  const float* bw2 = (const float*)d_in[3];
  const float* sw2 = (const float*)d_in[4];
  const float* bw3 = (const float*)d_in[5];
  const float* sw3 = (const float*)d_in[6];
  const float* w1  = (const float*)d_in[7];
  const float* b1  = (const float*)d_in[8];
  const float* w2  = (const float*)d_in[9];
  const float* b2  = (const float*)d_in[10];
  float* out = (float*)d_out;

  char* ws = (char*)d_ws;
  float* V1  = (float*)(ws);                       // 405 f
  float* V2  = (float*)(ws + 1664);                // 2025 f
  float* V3  = (float*)(ws + 9792);                // 810 f
  float* h1  = (float*)(ws + 16384);               // [2048,5,13,13]
  float* h2  = (float*)(ws + 16384 + 6922240);     // [2048,5,11,11]
  float* h3  = (float*)(ws + 16384 + 11878400);    // [2048,162]
  float* f1o = (float*)(ws + 16384 + 13205504);    // [2048,500]

  k_prep<<<8, 256, 0, stream>>>(bw1, sw1, bw2, sw2, bw3, sw3, V1, V2, V3);
  k_conv1_pool<<<1024, 256, 0, stream>>>(x, V1, h1);
  k_kanconv<5, 13, 5, 4><<<512, 256, 0, stream>>>(h1, V2, h2);
  k_kanconv<5, 11, 2, 4><<<512, 256, 0, stream>>>(h2, V3, h3);
  k_fc1<<<512, 256, 0, stream>>>(h3, w1, b1, f1o);
  k_fc2<<<512, 256, 0, stream>>>(f1o, w2, b2, out);
}

// Round 4
// 190.054 us; speedup vs baseline: 1.0590x; 1.0590x over previous
//
#include <hip/hip_runtime.h>

// ---------------------------------------------------------------------------
// KAN-conv MLP. Cardinal cubic B-spline: basis_j(x) = B3(u - j), u = 2.5x+5.5,
// only 4 taps nonzero. Per block: featurize G images once into LDS as bf16
// 12-slot records [B0..B7, silu, 0,0,0] (24 B, b64-aligned -> 3 ds_read_b64
// per tap, 2-way bank aliasing = free). Dense contraction with merged weights
// V[c][ky][kx][j9][o] (j8 = base weight, wave-uniform -> scalar loads).
// ---------------------------------------------------------------------------

__device__ __forceinline__ unsigned short f2bf(float x) {
  unsigned int b = __float_as_uint(x);
  b = b + 0x7fffu + ((b >> 16) & 1u);          // RNE
  return (unsigned short)(b >> 16);
}
__device__ __forceinline__ float bflo(unsigned int u) { return __uint_as_float(u << 16); }
__device__ __forceinline__ float bfhi(unsigned int u) { return __uint_as_float(u & 0xffff0000u); }

// All LDS stores through ushort view; record = 12 ushorts (24 B).
__device__ __forceinline__ void feat_store(float v, unsigned short* __restrict__ sp) {
  float s = v / (1.0f + __expf(-v));
  #pragma unroll
  for (int j = 0; j < 12; ++j) sp[j] = 0;
  sp[8] = f2bf(s);
  float u = fmaf(v, 2.5f, 5.5f);
  if (u >= 0.0f && u < 11.0f) {
    float tf = floorf(u);
    float f = u - tf, f2 = f * f, f3 = f2 * f, om = 1.0f - f;
    const float c6 = 1.0f / 6.0f;
    float w0 = om * om * om * c6;
    float w1 = (3.0f * f3 - 6.0f * f2 + 4.0f) * c6;
    float w2 = (-3.0f * f3 + 3.0f * f2 + 3.0f * f + 1.0f) * c6;
    float w3 = f3 * c6;
    int t = (int)tf;                           // 0..10; basis idx kept in [0,7]
    if (t >= 3)           sp[t - 3] = f2bf(w0);
    if (t >= 2 && t <= 9) sp[t - 2] = f2bf(w1);
    if (t >= 1 && t <= 8) sp[t - 1] = f2bf(w2);
    if (t <= 7)           sp[t]     = f2bf(w3);
  }
}

// Read one 12-slot record (first 9 values) as 3 x ds_read_b64.
__device__ __forceinline__ void read9(const unsigned int* __restrict__ up,
                                      float* __restrict__ ph) {
  uint2 a = *(const uint2*)(up);
  uint2 b = *(const uint2*)(up + 2);
  uint2 c = *(const uint2*)(up + 4);
  ph[0] = bflo(a.x); ph[1] = bfhi(a.x);
  ph[2] = bflo(a.y); ph[3] = bfhi(a.y);
  ph[4] = bflo(b.x); ph[5] = bfhi(b.x);
  ph[6] = bflo(b.y); ph[7] = bfhi(b.y);
  ph[8] = bflo(c.x);
}

// ---------------- weight prep: V[c][ky][kx][j(9)][o], j8 = base -------------
__global__ __launch_bounds__(256) void k_prep(
    const float* __restrict__ bw1, const float* __restrict__ sw1,
    const float* __restrict__ bw2, const float* __restrict__ sw2,
    const float* __restrict__ bw3, const float* __restrict__ sw3,
    float* __restrict__ V1, float* __restrict__ V2, float* __restrict__ V3) {
  int t = blockIdx.x * 256 + threadIdx.x;
  if (t < 405) {  // L1: CIN=1, COUT=5
    int o = t % 5, j = (t / 5) % 9, kx = (t / 45) % 3, ky = t / 135;
    int in = ky * 3 + kx;
    V1[t] = (j < 8) ? sw1[(o * 9 + in) * 8 + j] : bw1[o * 9 + in];
  }
  if (t < 2025) { // L2: CIN=5, COUT=5
    int o = t % 5, j = (t / 5) % 9, kx = (t / 45) % 3, ky = (t / 135) % 3, c = t / 405;
    int in = c * 9 + ky * 3 + kx;
    V2[t] = (j < 8) ? sw2[(o * 45 + in) * 8 + j] : bw2[o * 45 + in];
  }
  if (t < 810) {  // L3: CIN=5, COUT=2
    int o = t % 2, j = (t / 2) % 9, kx = (t / 18) % 3, ky = (t / 54) % 3, c = t / 162;
    int in = c * 9 + ky * 3 + kx;
    V3[t] = (j < 8) ? sw3[(o * 45 + in) * 8 + j] : bw3[o * 45 + in];
  }
}

// ---------------- conv1 (1->5) + 2x2 maxpool, 2 images/block ----------------
// LDS 37,632 B -> 4 blocks/CU; 1024 blocks = exactly 4/CU.
__global__ __launch_bounds__(256) void k_conv1_pool(
    const float* __restrict__ x, const float* __restrict__ Wd,
    float* __restrict__ h1) {
  __shared__ unsigned int phi[2 * 784 * 6];    // 37,632 B
  unsigned short* phs = (unsigned short*)phi;
  const int b0 = blockIdx.x * 2;
  for (int l = threadIdx.x; l < 2 * 784; l += 256)
    feat_store(x[b0 * 784 + l], &phs[l * 12]);
  __syncthreads();
  for (int it = threadIdx.x; it < 2 * 169; it += 256) {
    int i = it / 169, p = it % 169;
    int py = p / 13, px = p % 13;
    float best[5] = {-1e30f, -1e30f, -1e30f, -1e30f, -1e30f};
    #pragma unroll
    for (int dy = 0; dy < 2; ++dy) {
      #pragma unroll
      for (int dx = 0; dx < 2; ++dx) {
        int y = py * 2 + dy, xx = px * 2 + dx;
        float acc[5] = {0.f, 0.f, 0.f, 0.f, 0.f};
        #pragma unroll 1
        for (int ky = 0; ky < 3; ++ky) {
          const float* wp = Wd + ky * 135;     // [kx][j9][o5]
          const unsigned int* up = &phi[(i * 784 + (y + ky) * 28 + xx) * 6];
          #pragma unroll
          for (int kx = 0; kx < 3; ++kx) {
            float ph[9];
            read9(up + kx * 6, ph);
            #pragma unroll
            for (int j = 0; j < 9; ++j)
              #pragma unroll
              for (int o = 0; o < 5; ++o)
                acc[o] = fmaf(ph[j], wp[(kx * 9 + j) * 5 + o], acc[o]);
          }
        }
        #pragma unroll
        for (int o = 0; o < 5; ++o) best[o] = fmaxf(best[o], acc[o]);
      }
    }
    #pragma unroll
    for (int o = 0; o < 5; ++o)
      h1[((b0 + i) * 5 + o) * 169 + p] = best[o];
  }
}

// ---------------- generic KAN conv, G images/block, 2 images/thread ---------
template <int CIN, int HIN, int COUT, int G>
__global__ __launch_bounds__(256) void k_kanconv(
    const float* __restrict__ hin, const float* __restrict__ Wd,
    float* __restrict__ hout) {
  constexpr int HOUT = HIN - 2;
  constexpr int NPIX = CIN * HIN * HIN;
  __shared__ unsigned int phi[G * NPIX * 6];   // 24 B / pixel record
  unsigned short* phs = (unsigned short*)phi;
  const int b0 = blockIdx.x * G;
  for (int l = threadIdx.x; l < G * NPIX; l += 256)
    feat_store(hin[b0 * NPIX + l], &phs[l * 12]);
  __syncthreads();
  constexpr int NITEM = (G / 2) * HOUT * HOUT;
  int it = threadIdx.x;
  if (it >= NITEM) return;
  int ip = it / (HOUT * HOUT), pos = it % (HOUT * HOUT);
  int y = pos / HOUT, x = pos % HOUT;
  float acc[2][COUT];
  #pragma unroll
  for (int i = 0; i < 2; ++i)
    #pragma unroll
    for (int o = 0; o < COUT; ++o) acc[i][o] = 0.0f;
  #pragma unroll 1
  for (int cky = 0; cky < CIN * 3; ++cky) {
    int c = cky / 3, ky = cky % 3;
    const float* wp = Wd + cky * 27 * COUT;    // [kx][j9][o]
    #pragma unroll
    for (int i = 0; i < 2; ++i) {
      int img = ip * 2 + i;
      const unsigned int* up =
          &phi[(((img * CIN + c) * HIN + (y + ky)) * HIN + x) * 6];
      #pragma unroll
      for (int kx = 0; kx < 3; ++kx) {
        float ph[9];
        read9(up + kx * 6, ph);
        #pragma unroll
        for (int j = 0; j < 9; ++j)
          #pragma unroll
          for (int o = 0; o < COUT; ++o)
            acc[i][o] = fmaf(ph[j], wp[(kx * 9 + j) * COUT + o], acc[i][o]);
      }
    }
  }
  #pragma unroll
  for (int i = 0; i < 2; ++i)
    #pragma unroll
    for (int o = 0; o < COUT; ++o)
      hout[(((b0 + ip * 2 + i) * COUT + o) * HOUT + y) * HOUT + x] = acc[i][o];
}

// ---------------- FC1: [2048,162]x[500,162]^T + b, ReLU (32x64 tiles) -------
__global__ __launch_bounds__(256) void k_fc1(
    const float* __restrict__ A, const float* __restrict__ W,
    const float* __restrict__ bias, float* __restrict__ out) {
  __shared__ float As[16][34];
  __shared__ float Ws[16][68];
  int bm = (blockIdx.x & 63) * 32;
  int bn = (blockIdx.x >> 6) * 64;
  int tid = threadIdx.x;
  int tn = tid & 15, tm = tid >> 4;
  float acc[2][4];
  #pragma unroll
  for (int i = 0; i < 2; ++i)
    #pragma unroll
    for (int j = 0; j < 4; ++j) acc[i][j] = 0.0f;
  for (int k0 = 0; k0 < 162; k0 += 16) {
    #pragma unroll
    for (int e = 0; e < 2; ++e) {
      int l = tid + e * 256;
      int k = l & 15, m = l >> 4;
      int gk = k0 + k;
      As[k][m] = (gk < 162) ? A[(bm + m) * 162 + gk] : 0.0f;
    }
    #pragma unroll
    for (int e = 0; e < 4; ++e) {
      int l = tid + e * 256;
      int k = l & 15, n = l >> 4;
      int gk = k0 + k, gn = bn + n;
      Ws[k][n] = (gk < 162 && gn < 500) ? W[gn * 162 + gk] : 0.0f;
    }
    __syncthreads();
    #pragma unroll
    for (int k = 0; k < 16; ++k) {
      float a0 = As[k][tm * 2], a1 = As[k][tm * 2 + 1];
      float4 wv = *(const float4*)&Ws[k][tn * 4];
      float w4[4] = {wv.x, wv.y, wv.z, wv.w};
      #pragma unroll
      for (int j = 0; j < 4; ++j) {
        acc[0][j] = fmaf(a0, w4[j], acc[0][j]);
        acc[1][j] = fmaf(a1, w4[j], acc[1][j]);
      }
    }
    __syncthreads();
  }
  #pragma unroll
  for (int i = 0; i < 2; ++i) {
    int m = bm + tm * 2 + i;
    #pragma unroll
    for (int j = 0; j < 4; ++j) {
      int n = bn + tn * 4 + j;
      if (n < 500) {
        float v = acc[i][j] + bias[n];
        out[m * 500 + n] = v > 0.0f ? v : 0.0f;
      }
    }
  }
}

// ---------------- FC2: [2048,500]x[10,500]^T + b ---------------------------
__global__ __launch_bounds__(256) void k_fc2(
    const float* __restrict__ H, const float* __restrict__ W2,
    const float* __restrict__ b2, float* __restrict__ out) {
  int gtid = blockIdx.x * 256 + threadIdx.x;
  int b = gtid / 64, lane = gtid % 64;
  if (b >= 2048) return;
  float acc[10];
  #pragma unroll
  for (int o = 0; o < 10; ++o) acc[o] = 0.0f;
  for (int k = lane; k < 500; k += 64) {
    float a = H[b * 500 + k];
    #pragma unroll
    for (int o = 0; o < 10; ++o) acc[o] = fmaf(a, W2[o * 500 + k], acc[o]);
  }
  #pragma unroll
  for (int off = 32; off > 0; off >>= 1) {
    #pragma unroll
    for (int o = 0; o < 10; ++o) acc[o] += __shfl_down(acc[o], off);
  }
  if (lane == 0) {
    #pragma unroll
    for (int o = 0; o < 10; ++o) out[b * 10 + o] = acc[o] + b2[o];
  }
}

// ---------------------------------------------------------------------------
extern "C" void kernel_launch(void* const* d_in, const int* in_sizes, int n_in,
                              void* d_out, int out_size, void* d_ws, size_t ws_size,
                              hipStream_t stream) {
  (void)in_sizes; (void)n_in; (void)out_size; (void)ws_size;
  const float* x   = (const float*)d_in[0];
  const float* bw1 = (const float*)d_in[1];
  const float* sw1 = (const float*)d_in[2];
  const float* bw2 = (const float*)d_in[3];
  const float* sw2 = (const float*)d_in[4];
  const float* bw3 = (const float*)d_in[5];
  const float* sw3 = (const float*)d_in[6];
  const float* w1  = (const float*)d_in[7];
  const float* b1  = (const float*)d_in[8];
  const float* w2  = (const float*)d_in[9];
  const float* b2  = (const float*)d_in[10];
  float* out = (float*)d_out;

  char* ws = (char*)d_ws;
  float* V1  = (float*)(ws);                       // 405 f
  float* V2  = (float*)(ws + 1664);                // 2025 f
  float* V3  = (float*)(ws + 9792);                // 810 f
  float* h1  = (float*)(ws + 16384);               // [2048,5,13,13]
  float* h2  = (float*)(ws + 16384 + 6922240);     // [2048,5,11,11]
  float* h3  = (float*)(ws + 16384 + 11878400);    // [2048,162]
  float* f1o = (float*)(ws + 16384 + 13205504);    // [2048,500]

  k_prep<<<8, 256, 0, stream>>>(bw1, sw1, bw2, sw2, bw3, sw3, V1, V2, V3);
  k_conv1_pool<<<1024, 256, 0, stream>>>(x, V1, h1);
  k_kanconv<5, 13, 5, 4><<<512, 256, 0, stream>>>(h1, V2, h2);
  k_kanconv<5, 11, 2, 4><<<512, 256, 0, stream>>>(h2, V3, h3);
  k_fc1<<<512, 256, 0, stream>>>(h3, w1, b1, f1o);
  k_fc2<<<512, 256, 0, stream>>>(f1o, w2, b2, out);
}

// Round 5
// 170.321 us; speedup vs baseline: 1.1817x; 1.1159x over previous
//
#include <hip/hip_runtime.h>

// ---------------------------------------------------------------------------
// KAN-conv MLP. Cardinal cubic B-spline: basis_j(x) = B3(u - j), u = 2.5x+5.5,
// only 4 taps nonzero. Per block: featurize G images once into LDS as bf16
// 12-slot records [B0..B7, silu, 0,0,0] (24 B, b64-aligned -> 3 ds_read_b64
// per tap). Dense contraction with merged weights V[c][ky][kx][j9][o]
// (j8 = base weight, wave-uniform -> scalar loads). G chosen for >=3
// blocks/CU residency (LDS-capacity) -- R4's G=4 gave 1 block/CU and was
// 80% lgkmcnt-stall.
// ---------------------------------------------------------------------------

__device__ __forceinline__ unsigned short f2bf(float x) {
  unsigned int b = __float_as_uint(x);
  b = b + 0x7fffu + ((b >> 16) & 1u);          // RNE
  return (unsigned short)(b >> 16);
}
__device__ __forceinline__ float bflo(unsigned int u) { return __uint_as_float(u << 16); }
__device__ __forceinline__ float bfhi(unsigned int u) { return __uint_as_float(u & 0xffff0000u); }

// All LDS stores through ushort view; record = 12 ushorts (24 B).
__device__ __forceinline__ void feat_store(float v, unsigned short* __restrict__ sp) {
  float s = v / (1.0f + __expf(-v));
  #pragma unroll
  for (int j = 0; j < 12; ++j) sp[j] = 0;
  sp[8] = f2bf(s);
  float u = fmaf(v, 2.5f, 5.5f);
  if (u >= 0.0f && u < 11.0f) {
    float tf = floorf(u);
    float f = u - tf, f2 = f * f, f3 = f2 * f, om = 1.0f - f;
    const float c6 = 1.0f / 6.0f;
    float w0 = om * om * om * c6;
    float w1 = (3.0f * f3 - 6.0f * f2 + 4.0f) * c6;
    float w2 = (-3.0f * f3 + 3.0f * f2 + 3.0f * f + 1.0f) * c6;
    float w3 = f3 * c6;
    int t = (int)tf;                           // 0..10; basis idx kept in [0,7]
    if (t >= 3)           sp[t - 3] = f2bf(w0);
    if (t >= 2 && t <= 9) sp[t - 2] = f2bf(w1);
    if (t >= 1 && t <= 8) sp[t - 1] = f2bf(w2);
    if (t <= 7)           sp[t]     = f2bf(w3);
  }
}

// Read one 12-slot record (first 9 values) as 3 x ds_read_b64.
__device__ __forceinline__ void read9(const unsigned int* __restrict__ up,
                                      float* __restrict__ ph) {
  uint2 a = *(const uint2*)(up);
  uint2 b = *(const uint2*)(up + 2);
  uint2 c = *(const uint2*)(up + 4);
  ph[0] = bflo(a.x); ph[1] = bfhi(a.x);
  ph[2] = bflo(a.y); ph[3] = bfhi(a.y);
  ph[4] = bflo(b.x); ph[5] = bfhi(b.x);
  ph[6] = bflo(b.y); ph[7] = bfhi(b.y);
  ph[8] = bflo(c.x);
}

// ---------------- weight prep: V[c][ky][kx][j(9)][o], j8 = base -------------
__global__ __launch_bounds__(256) void k_prep(
    const float* __restrict__ bw1, const float* __restrict__ sw1,
    const float* __restrict__ bw2, const float* __restrict__ sw2,
    const float* __restrict__ bw3, const float* __restrict__ sw3,
    float* __restrict__ V1, float* __restrict__ V2, float* __restrict__ V3) {
  int t = blockIdx.x * 256 + threadIdx.x;
  if (t < 405) {  // L1: CIN=1, COUT=5
    int o = t % 5, j = (t / 5) % 9, kx = (t / 45) % 3, ky = t / 135;
    int in = ky * 3 + kx;
    V1[t] = (j < 8) ? sw1[(o * 9 + in) * 8 + j] : bw1[o * 9 + in];
  }
  if (t < 2025) { // L2: CIN=5, COUT=5
    int o = t % 5, j = (t / 5) % 9, kx = (t / 45) % 3, ky = (t / 135) % 3, c = t / 405;
    int in = c * 9 + ky * 3 + kx;
    V2[t] = (j < 8) ? sw2[(o * 45 + in) * 8 + j] : bw2[o * 45 + in];
  }
  if (t < 810) {  // L3: CIN=5, COUT=2
    int o = t % 2, j = (t / 2) % 9, kx = (t / 18) % 3, ky = (t / 54) % 3, c = t / 162;
    int in = c * 9 + ky * 3 + kx;
    V3[t] = (j < 8) ? sw3[(o * 45 + in) * 8 + j] : bw3[o * 45 + in];
  }
}

// ---------------- conv1 (1->5) + 2x2 maxpool, ONE image per block -----------
// LDS 18,816 B -> 8 blocks/CU; grid 2048 = 8/CU, all resident.
__global__ __launch_bounds__(256) void k_conv1_pool(
    const float* __restrict__ x, const float* __restrict__ Wd,
    float* __restrict__ h1) {
  __shared__ unsigned int phi[784 * 6];        // 18,816 B
  unsigned short* phs = (unsigned short*)phi;
  const int b = blockIdx.x;
  for (int l = threadIdx.x; l < 784; l += 256)
    feat_store(x[b * 784 + l], &phs[l * 12]);
  __syncthreads();
  int p = threadIdx.x;
  if (p >= 169) return;
  int py = p / 13, px = p % 13;
  float best[5] = {-1e30f, -1e30f, -1e30f, -1e30f, -1e30f};
  #pragma unroll
  for (int dy = 0; dy < 2; ++dy) {
    #pragma unroll
    for (int dx = 0; dx < 2; ++dx) {
      int y = py * 2 + dy, xx = px * 2 + dx;
      float acc[5] = {0.f, 0.f, 0.f, 0.f, 0.f};
      #pragma unroll 1
      for (int ky = 0; ky < 3; ++ky) {
        const float* wp = Wd + ky * 135;       // [kx][j9][o5]
        const unsigned int* up = &phi[((y + ky) * 28 + xx) * 6];
        #pragma unroll
        for (int kx = 0; kx < 3; ++kx) {
          float ph[9];
          read9(up + kx * 6, ph);
          #pragma unroll
          for (int j = 0; j < 9; ++j)
            #pragma unroll
            for (int o = 0; o < 5; ++o)
              acc[o] = fmaf(ph[j], wp[(kx * 9 + j) * 5 + o], acc[o]);
        }
      }
      #pragma unroll
      for (int o = 0; o < 5; ++o) best[o] = fmaxf(best[o], acc[o]);
    }
  }
  #pragma unroll
  for (int o = 0; o < 5; ++o)
    h1[((b * 5 + o) * 169) + p] = best[o];
}

// ---------------- generic KAN conv, G images/block, 1 item/thread -----------
template <int CIN, int HIN, int COUT, int G>
__global__ __launch_bounds__(256) void k_kanconv(
    const float* __restrict__ hin, const float* __restrict__ Wd,
    float* __restrict__ hout, int nimg) {
  constexpr int HOUT = HIN - 2;
  constexpr int NPIX = CIN * HIN * HIN;
  __shared__ unsigned int phi[G * NPIX * 6];   // 24 B / pixel record
  unsigned short* phs = (unsigned short*)phi;
  const int b0 = blockIdx.x * G;
  const int nloc = (nimg - b0 < G) ? (nimg - b0) : G;
  for (int l = threadIdx.x; l < nloc * NPIX; l += 256)
    feat_store(hin[b0 * NPIX + l], &phs[l * 12]);
  __syncthreads();
  int it = threadIdx.x;
  if (it >= nloc * HOUT * HOUT) return;
  int img = it / (HOUT * HOUT), pos = it % (HOUT * HOUT);
  int y = pos / HOUT, x = pos % HOUT;
  float acc[COUT];
  #pragma unroll
  for (int o = 0; o < COUT; ++o) acc[o] = 0.0f;
  #pragma unroll 1
  for (int cky = 0; cky < CIN * 3; ++cky) {
    int c = cky / 3, ky = cky % 3;
    const float* wp = Wd + cky * 27 * COUT;    // [kx][j9][o]
    const unsigned int* up =
        &phi[(((img * CIN + c) * HIN + (y + ky)) * HIN + x) * 6];
    #pragma unroll
    for (int kx = 0; kx < 3; ++kx) {
      float ph[9];
      read9(up + kx * 6, ph);
      #pragma unroll
      for (int j = 0; j < 9; ++j)
        #pragma unroll
        for (int o = 0; o < COUT; ++o)
          acc[o] = fmaf(ph[j], wp[(kx * 9 + j) * COUT + o], acc[o]);
    }
  }
  #pragma unroll
  for (int o = 0; o < COUT; ++o)
    hout[(((b0 + img) * COUT + o) * HOUT + y) * HOUT + x] = acc[o];
}

// ---------------- FC1: [2048,162]x[500,162]^T + b, ReLU (32x64 tiles) -------
__global__ __launch_bounds__(256) void k_fc1(
    const float* __restrict__ A, const float* __restrict__ W,
    const float* __restrict__ bias, float* __restrict__ out) {
  __shared__ float As[16][34];
  __shared__ float Ws[16][68];
  int bm = (blockIdx.x & 63) * 32;
  int bn = (blockIdx.x >> 6) * 64;
  int tid = threadIdx.x;
  int tn = tid & 15, tm = tid >> 4;
  float acc[2][4];
  #pragma unroll
  for (int i = 0; i < 2; ++i)
    #pragma unroll
    for (int j = 0; j < 4; ++j) acc[i][j] = 0.0f;
  for (int k0 = 0; k0 < 162; k0 += 16) {
    #pragma unroll
    for (int e = 0; e < 2; ++e) {
      int l = tid + e * 256;
      int k = l & 15, m = l >> 4;
      int gk = k0 + k;
      As[k][m] = (gk < 162) ? A[(bm + m) * 162 + gk] : 0.0f;
    }
    #pragma unroll
    for (int e = 0; e < 4; ++e) {
      int l = tid + e * 256;
      int k = l & 15, n = l >> 4;
      int gk = k0 + k, gn = bn + n;
      Ws[k][n] = (gk < 162 && gn < 500) ? W[gn * 162 + gk] : 0.0f;
    }
    __syncthreads();
    #pragma unroll
    for (int k = 0; k < 16; ++k) {
      float a0 = As[k][tm * 2], a1 = As[k][tm * 2 + 1];
      float4 wv = *(const float4*)&Ws[k][tn * 4];
      float w4[4] = {wv.x, wv.y, wv.z, wv.w};
      #pragma unroll
      for (int j = 0; j < 4; ++j) {
        acc[0][j] = fmaf(a0, w4[j], acc[0][j]);
        acc[1][j] = fmaf(a1, w4[j], acc[1][j]);
      }
    }
    __syncthreads();
  }
  #pragma unroll
  for (int i = 0; i < 2; ++i) {
    int m = bm + tm * 2 + i;
    #pragma unroll
    for (int j = 0; j < 4; ++j) {
      int n = bn + tn * 4 + j;
      if (n < 500) {
        float v = acc[i][j] + bias[n];
        out[m * 500 + n] = v > 0.0f ? v : 0.0f;
      }
    }
  }
}

// ---------------- FC2: [2048,500]x[10,500]^T + b ---------------------------
__global__ __launch_bounds__(256) void k_fc2(
    const float* __restrict__ H, const float* __restrict__ W2,
    const float* __restrict__ b2, float* __restrict__ out) {
  int gtid = blockIdx.x * 256 + threadIdx.x;
  int b = gtid / 64, lane = gtid % 64;
  if (b >= 2048) return;
  float acc[10];
  #pragma unroll
  for (int o = 0; o < 10; ++o) acc[o] = 0.0f;
  for (int k = lane; k < 500; k += 64) {
    float a = H[b * 500 + k];
    #pragma unroll
    for (int o = 0; o < 10; ++o) acc[o] = fmaf(a, W2[o * 500 + k], acc[o]);
  }
  #pragma unroll
  for (int off = 32; off > 0; off >>= 1) {
    #pragma unroll
    for (int o = 0; o < 10; ++o) acc[o] += __shfl_down(acc[o], off);
  }
  if (lane == 0) {
    #pragma unroll
    for (int o = 0; o < 10; ++o) out[b * 10 + o] = acc[o] + b2[o];
  }
}

// ---------------------------------------------------------------------------
extern "C" void kernel_launch(void* const* d_in, const int* in_sizes, int n_in,
                              void* d_out, int out_size, void* d_ws, size_t ws_size,
                              hipStream_t stream) {
  (void)in_sizes; (void)n_in; (void)out_size; (void)ws_size;
  const float* x   = (const float*)d_in[0];
  const float* bw1 = (const float*)d_in[1];
  const float* sw1 = (const float*)d_in[2];
  const float* bw2 = (const float*)d_in[3];
  const float* sw2 = (const float*)d_in[4];
  const float* bw3 = (const float*)d_in[5];
  const float* sw3 = (const float*)d_in[6];
  const float* w1  = (const float*)d_in[7];
  const float* b1  = (const float*)d_in[8];
  const float* w2  = (const float*)d_in[9];
  const float* b2  = (const float*)d_in[10];
  float* out = (float*)d_out;

  char* ws = (char*)d_ws;
  float* V1  = (float*)(ws);                       // 405 f
  float* V2  = (float*)(ws + 1664);                // 2025 f
  float* V3  = (float*)(ws + 9792);                // 810 f
  float* h1  = (float*)(ws + 16384);               // [2048,5,13,13]
  float* h2  = (float*)(ws + 16384 + 6922240);     // [2048,5,11,11]
  float* h3  = (float*)(ws + 16384 + 11878400);    // [2048,162]
  float* f1o = (float*)(ws + 16384 + 13205504);    // [2048,500]

  k_prep<<<8, 256, 0, stream>>>(bw1, sw1, bw2, sw2, bw3, sw3, V1, V2, V3);
  k_conv1_pool<<<2048, 256, 0, stream>>>(x, V1, h1);
  k_kanconv<5, 13, 5, 2><<<1024, 256, 0, stream>>>(h1, V2, h2, 2048);
  k_kanconv<5, 11, 2, 3><<<683, 256, 0, stream>>>(h2, V3, h3, 2048);
  k_fc1<<<512, 256, 0, stream>>>(h3, w1, b1, f1o);
  k_fc2<<<512, 256, 0, stream>>>(f1o, w2, b2, out);
}

// Round 6
// 163.825 us; speedup vs baseline: 1.2286x; 1.0397x over previous
//
#include <hip/hip_runtime.h>

// ---------------------------------------------------------------------------
// Fully-fused KAN-conv MLP: one block = one image through all layers.
// Cardinal cubic B-spline: basis_j(x) = B3(u - j), u = 2.5x+5.5 (4 taps).
// phi records: 12 bf16 slots [B0..B7, silu, 0,0,0] (24 B, 3x ds_read_b64).
// Conv weights merged V[c][ky][kx][j9][o] (j8 = base weight) -> s_loads.
// fc1 weights transposed+bf16-packed W1t[k(164)][u(256)] (outs 2u,2u+1).
// ---------------------------------------------------------------------------

__device__ __forceinline__ unsigned short f2bf(float x) {
  unsigned int b = __float_as_uint(x);
  b = b + 0x7fffu + ((b >> 16) & 1u);          // RNE
  return (unsigned short)(b >> 16);
}
__device__ __forceinline__ float bflo(unsigned int u) { return __uint_as_float(u << 16); }
__device__ __forceinline__ float bfhi(unsigned int u) { return __uint_as_float(u & 0xffff0000u); }

__device__ __forceinline__ void feat_store(float v, unsigned short* __restrict__ sp) {
  float s = v / (1.0f + __expf(-v));
  #pragma unroll
  for (int j = 0; j < 12; ++j) sp[j] = 0;
  sp[8] = f2bf(s);
  float u = fmaf(v, 2.5f, 5.5f);
  if (u >= 0.0f && u < 11.0f) {
    float tf = floorf(u);
    float f = u - tf, f2 = f * f, f3 = f2 * f, om = 1.0f - f;
    const float c6 = 1.0f / 6.0f;
    float w0 = om * om * om * c6;
    float w1 = (3.0f * f3 - 6.0f * f2 + 4.0f) * c6;
    float w2 = (-3.0f * f3 + 3.0f * f2 + 3.0f * f + 1.0f) * c6;
    float w3 = f3 * c6;
    int t = (int)tf;
    if (t >= 3)           sp[t - 3] = f2bf(w0);
    if (t >= 2 && t <= 9) sp[t - 2] = f2bf(w1);
    if (t >= 1 && t <= 8) sp[t - 1] = f2bf(w2);
    if (t <= 7)           sp[t]     = f2bf(w3);
  }
}

__device__ __forceinline__ void read9(const unsigned int* __restrict__ up,
                                      float* __restrict__ ph) {
  uint2 a = *(const uint2*)(up);
  uint2 b = *(const uint2*)(up + 2);
  uint2 c = *(const uint2*)(up + 4);
  ph[0] = bflo(a.x); ph[1] = bfhi(a.x);
  ph[2] = bflo(a.y); ph[3] = bfhi(a.y);
  ph[4] = bflo(b.x); ph[5] = bfhi(b.x);
  ph[6] = bflo(b.y); ph[7] = bfhi(b.y);
  ph[8] = bflo(c.x);
}

// ---------------- prep: V1/V2/V3 merged conv weights + W1t bf16 -------------
__global__ __launch_bounds__(256) void k_prep(
    const float* __restrict__ bw1, const float* __restrict__ sw1,
    const float* __restrict__ bw2, const float* __restrict__ sw2,
    const float* __restrict__ bw3, const float* __restrict__ sw3,
    const float* __restrict__ w1,
    float* __restrict__ V1, float* __restrict__ V2, float* __restrict__ V3,
    unsigned int* __restrict__ W1t) {
  int t = blockIdx.x * 256 + threadIdx.x;
  if (t < 405) {  // L1: CIN=1, COUT=5  idx=((ky*3+kx)*9+j)*5+o
    int o = t % 5, j = (t / 5) % 9, kx = (t / 45) % 3, ky = t / 135;
    int in = ky * 3 + kx;
    V1[t] = (j < 8) ? sw1[(o * 9 + in) * 8 + j] : bw1[o * 9 + in];
  }
  if (t < 2025) { // L2: CIN=5, COUT=5  idx=(((c*3+ky)*3+kx)*9+j)*5+o
    int o = t % 5, j = (t / 5) % 9, kx = (t / 45) % 3, ky = (t / 135) % 3, c = t / 405;
    int in = c * 9 + ky * 3 + kx;
    V2[t] = (j < 8) ? sw2[(o * 45 + in) * 8 + j] : bw2[o * 45 + in];
  }
  if (t < 810) {  // L3: CIN=5, COUT=2  idx=(((c*3+ky)*3+kx)*9+j)*2+o
    int o = t % 2, j = (t / 2) % 9, kx = (t / 18) % 3, ky = (t / 54) % 3, c = t / 162;
    int in = c * 9 + ky * 3 + kx;
    V3[t] = (j < 8) ? sw3[(o * 45 + in) * 8 + j] : bw3[o * 45 + in];
  }
  if (t < 164 * 256) { // W1t[k][u] packs outputs (2u, 2u+1); k padded to 164
    int k = t / 256, u = t % 256;
    int o0 = 2 * u, o1 = 2 * u + 1;
    unsigned int lo = (k < 162 && o0 < 500) ? f2bf(w1[o0 * 162 + k]) : 0;
    unsigned int hi = (k < 162 && o1 < 500) ? f2bf(w1[o1 * 162 + k]) : 0;
    W1t[t] = lo | (hi << 16);
  }
}

// ---------------- the fused per-image kernel --------------------------------
__global__ __launch_bounds__(256) void k_fused(
    const float* __restrict__ x,
    const float* __restrict__ V1, const float* __restrict__ V2,
    const float* __restrict__ V3,
    const unsigned int* __restrict__ W1t,
    const float* __restrict__ b1,
    const float* __restrict__ W2, const float* __restrict__ b2,
    float* __restrict__ out) {
  __shared__ unsigned int phi[845 * 6];   // 20,280 B  (max of 784/845/605 recs)
  __shared__ float hbuf[845];             //  3,380 B  (h1/h2/h3/fc1out/partials)
  unsigned short* phs = (unsigned short*)phi;
  const int b = blockIdx.x;
  const int tid = threadIdx.x;

  // P1: featurize input image (784 px)
  for (int l = tid; l < 784; l += 256)
    feat_store(x[b * 784 + l], &phs[l * 12]);
  __syncthreads();

  // P2: conv1 (1->5) + 2x2 maxpool -> h1 = hbuf[o*169 + p]
  if (tid < 169) {
    int py = tid / 13, px = tid % 13;
    int r0 = py * 2, c0 = px * 2;
    float wacc[4][5];
    #pragma unroll
    for (int wi = 0; wi < 4; ++wi)
      #pragma unroll
      for (int o = 0; o < 5; ++o) wacc[wi][o] = 0.0f;
    #pragma unroll
    for (int r = 0; r < 4; ++r) {
      #pragma unroll
      for (int c = 0; c < 4; ++c) {
        float ph[9];
        read9(&phi[((r0 + r) * 28 + c0 + c) * 6], ph);
        #pragma unroll
        for (int dy = 0; dy < 2; ++dy) {
          #pragma unroll
          for (int dx = 0; dx < 2; ++dx) {
            int ky = r - dy, kx = c - dx;
            if (ky >= 0 && ky < 3 && kx >= 0 && kx < 3) {
              const float* wp = V1 + (ky * 3 + kx) * 45;
              #pragma unroll
              for (int j = 0; j < 9; ++j)
                #pragma unroll
                for (int o = 0; o < 5; ++o)
                  wacc[dy * 2 + dx][o] = fmaf(ph[j], wp[j * 5 + o], wacc[dy * 2 + dx][o]);
            }
          }
        }
      }
    }
    #pragma unroll
    for (int o = 0; o < 5; ++o) {
      float m = fmaxf(fmaxf(wacc[0][o], wacc[1][o]), fmaxf(wacc[2][o], wacc[3][o]));
      hbuf[o * 169 + tid] = m;
    }
  }
  __syncthreads();

  // P3: featurize h1 (845 px)
  for (int l = tid; l < 845; l += 256)
    feat_store(hbuf[l], &phs[l * 12]);
  __syncthreads();

  // P4: conv2 (5->5) -> h2 = hbuf[o*121 + pos]
  if (tid < 121) {
    int y = tid / 11, xx = tid % 11;
    float acc[5] = {0.f, 0.f, 0.f, 0.f, 0.f};
    #pragma unroll 1
    for (int cky = 0; cky < 15; ++cky) {
      int c = cky / 3, ky = cky % 3;
      const float* wp = V2 + cky * 135;      // [kx][j9][o5]
      const unsigned int* up = &phi[(c * 169 + (y + ky) * 13 + xx) * 6];
      #pragma unroll
      for (int kx = 0; kx < 3; ++kx) {
        float ph[9];
        read9(up + kx * 6, ph);
        #pragma unroll
        for (int j = 0; j < 9; ++j)
          #pragma unroll
          for (int o = 0; o < 5; ++o)
            acc[o] = fmaf(ph[j], wp[(kx * 9 + j) * 5 + o], acc[o]);
      }
    }
    #pragma unroll
    for (int o = 0; o < 5; ++o) hbuf[o * 121 + tid] = acc[o];
  }
  __syncthreads();

  // P5: featurize h2 (605 px)
  for (int l = tid; l < 605; l += 256)
    feat_store(hbuf[l], &phs[l * 12]);
  __syncthreads();

  // P6: conv3 (5->2) -> h3 = hbuf[o*81 + pos]; pad hbuf[162..163]=0
  if (tid < 81) {
    int y = tid / 9, xx = tid % 9;
    float acc[2] = {0.f, 0.f};
    #pragma unroll 1
    for (int cky = 0; cky < 15; ++cky) {
      int c = cky / 3, ky = cky % 3;
      const float* wp = V3 + cky * 54;       // [kx][j9][o2]
      const unsigned int* up = &phi[(c * 121 + (y + ky) * 11 + xx) * 6];
      #pragma unroll
      for (int kx = 0; kx < 3; ++kx) {
        float ph[9];
        read9(up + kx * 6, ph);
        #pragma unroll
        for (int j = 0; j < 9; ++j)
          #pragma unroll
          for (int o = 0; o < 2; ++o)
            acc[o] = fmaf(ph[j], wp[kx * 18 + j * 2 + o], acc[o]);
      }
    }
    hbuf[tid] = acc[0];
    hbuf[81 + tid] = acc[1];
  }
  if (tid == 81) { hbuf[162] = 0.0f; hbuf[163] = 0.0f; }
  __syncthreads();

  // P7: fc1 (162->500) + bias + ReLU -> hbuf[200 + o]
  if (tid < 250) {
    float a0 = 0.0f, a1 = 0.0f;
    #pragma unroll 1
    for (int k4 = 0; k4 < 41; ++k4) {
      float4 h = *(const float4*)&hbuf[k4 * 4];
      unsigned int w0 = W1t[(k4 * 4 + 0) * 256 + tid];
      unsigned int w1v = W1t[(k4 * 4 + 1) * 256 + tid];
      unsigned int w2v = W1t[(k4 * 4 + 2) * 256 + tid];
      unsigned int w3v = W1t[(k4 * 4 + 3) * 256 + tid];
      a0 = fmaf(bflo(w0), h.x, a0);  a1 = fmaf(bfhi(w0), h.x, a1);
      a0 = fmaf(bflo(w1v), h.y, a0); a1 = fmaf(bfhi(w1v), h.y, a1);
      a0 = fmaf(bflo(w2v), h.z, a0); a1 = fmaf(bfhi(w2v), h.z, a1);
      a0 = fmaf(bflo(w3v), h.w, a0); a1 = fmaf(bfhi(w3v), h.w, a1);
    }
    int o0 = 2 * tid, o1 = 2 * tid + 1;
    float v0 = a0 + b1[o0], v1 = a1 + b1[o1];
    hbuf[200 + o0] = v0 > 0.0f ? v0 : 0.0f;
    hbuf[200 + o1] = v1 > 0.0f ? v1 : 0.0f;
  }
  __syncthreads();

  // P8: fc2 partials: (o,part) -> hbuf[o*16+part], k = part*32 .. +31
  if (tid < 160) {
    int o = tid >> 4, part = tid & 15;
    float s = 0.0f;
    #pragma unroll
    for (int j = 0; j < 8; ++j) {
      int k = part * 32 + j * 4;
      if (k < 500) {
        float4 w = *(const float4*)&W2[o * 500 + k];
        float4 h = *(const float4*)&hbuf[200 + k];
        s += w.x * h.x + w.y * h.y + w.z * h.z + w.w * h.w;
      }
    }
    hbuf[tid] = s;
  }
  __syncthreads();

  // P9: reduce 16 partials per output, add bias, store
  if (tid < 10) {
    float s = 0.0f;
    #pragma unroll
    for (int p = 0; p < 16; ++p) s += hbuf[tid * 16 + p];
    out[b * 10 + tid] = s + b2[tid];
  }
}

// ---------------------------------------------------------------------------
extern "C" void kernel_launch(void* const* d_in, const int* in_sizes, int n_in,
                              void* d_out, int out_size, void* d_ws, size_t ws_size,
                              hipStream_t stream) {
  (void)in_sizes; (void)n_in; (void)out_size; (void)ws_size;
  const float* x   = (const float*)d_in[0];
  const float* bw1 = (const float*)d_in[1];
  const float* sw1 = (const float*)d_in[2];
  const float* bw2 = (const float*)d_in[3];
  const float* sw2 = (const float*)d_in[4];
  const float* bw3 = (const float*)d_in[5];
  const float* sw3 = (const float*)d_in[6];
  const float* w1  = (const float*)d_in[7];
  const float* b1  = (const float*)d_in[8];
  const float* w2  = (const float*)d_in[9];
  const float* b2  = (const float*)d_in[10];
  float* out = (float*)d_out;

  char* ws = (char*)d_ws;
  float*        V1  = (float*)(ws);               // 405 f  (1,620 B)
  float*        V2  = (float*)(ws + 2048);        // 2025 f (8,100 B)
  float*        V3  = (float*)(ws + 10752);       // 810 f  (3,240 B)
  unsigned int* W1t = (unsigned int*)(ws + 14336);// 164*256 uints (167,936 B)

  k_prep<<<164, 256, 0, stream>>>(bw1, sw1, bw2, sw2, bw3, sw3, w1,
                                  V1, V2, V3, W1t);
  k_fused<<<2048, 256, 0, stream>>>(x, V1, V2, V3, W1t, b1, w2, b2, out);
}